// Round 1
// baseline (203.579 us; speedup 1.0000x reference)
//
#include <hip/hip_runtime.h>
#include <hip/hip_bf16.h>

// ---------------------------------------------------------------------------
// Kernel 1: full CNN per image. One 256-thread block per image.
// sequence [T,1,28,28] -> digit_probs [T,10] (written twice: digit + guard).
// ReLU+avgpool fused into each conv: each pooled output = 0.25*sum of 4
// relu(conv) values; pre-pool maps never materialized.
// ---------------------------------------------------------------------------
__global__ __launch_bounds__(256) void cnn_kernel(
    const float* __restrict__ seq,
    const float* __restrict__ w1, const float* __restrict__ b1,
    const float* __restrict__ w2, const float* __restrict__ b2,
    const float* __restrict__ w3, const float* __restrict__ b3,
    const float* __restrict__ wd, const float* __restrict__ bd,
    float* __restrict__ out, int guard_off)
{
    const int img = blockIdx.x;
    const int tid = threadIdx.x;
    const float* __restrict__ x = seq + (size_t)img * 784;

    __shared__ float s_img[784];
    __shared__ float s_w1[72],   s_b1[8];
    __shared__ float s_w2[1152], s_b2[16];
    __shared__ float s_w3[4608], s_b3[32];
    __shared__ float s_wd[320],  s_bd[10];
    __shared__ float a1[8][13][13];   // pooled conv1
    __shared__ float a2[16][5][5];    // pooled conv2
    __shared__ float a3p[32][4];      // conv3 pre-pool (2x2)
    __shared__ float a3[32];          // pooled conv3 (flatten)
    __shared__ float logits[10];

    for (int i = tid; i < 784;  i += 256) s_img[i] = x[i];
    for (int i = tid; i < 72;   i += 256) s_w1[i]  = w1[i];
    for (int i = tid; i < 1152; i += 256) s_w2[i]  = w2[i];
    for (int i = tid; i < 4608; i += 256) s_w3[i]  = w3[i];
    for (int i = tid; i < 320;  i += 256) s_wd[i]  = wd[i];
    if (tid < 8)  s_b1[tid] = b1[tid];
    if (tid < 16) s_b2[tid] = b2[tid];
    if (tid < 32) s_b3[tid] = b3[tid];
    if (tid < 10) s_bd[tid] = bd[tid];
    __syncthreads();

    // ---- conv1 (1->8, 3x3) + relu + 2x2 avgpool: 8*13*13 = 1352 outputs ----
    for (int idx = tid; idx < 1352; idx += 256) {
        const int c = idx / 169, r = idx % 169, y = r / 13, xo = r % 13;
        const float* wc = &s_w1[c * 9];
        float acc = 0.f;
        #pragma unroll
        for (int dy = 0; dy < 2; ++dy) {
            #pragma unroll
            for (int dx = 0; dx < 2; ++dx) {
                const int iy = 2 * y + dy, ix = 2 * xo + dx;
                float s = s_b1[c];
                #pragma unroll
                for (int ky = 0; ky < 3; ++ky)
                    #pragma unroll
                    for (int kx = 0; kx < 3; ++kx)
                        s += s_img[(iy + ky) * 28 + ix + kx] * wc[ky * 3 + kx];
                acc += fmaxf(s, 0.f);
            }
        }
        a1[c][y][xo] = acc * 0.25f;
    }
    __syncthreads();

    // ---- conv2 (8->16, 3x3) + relu + pool: 16*5*5 = 400 outputs ----
    for (int idx = tid; idx < 400; idx += 256) {
        const int c = idx / 25, r = idx % 25, y = r / 5, xo = r % 5;
        const float* wc = &s_w2[c * 72];
        float acc = 0.f;
        #pragma unroll
        for (int dy = 0; dy < 2; ++dy) {
            #pragma unroll
            for (int dx = 0; dx < 2; ++dx) {
                const int iy = 2 * y + dy, ix = 2 * xo + dx;
                float s = s_b2[c];
                for (int ci = 0; ci < 8; ++ci) {
                    const float* wci = &wc[ci * 9];
                    #pragma unroll
                    for (int ky = 0; ky < 3; ++ky)
                        #pragma unroll
                        for (int kx = 0; kx < 3; ++kx)
                            s += a1[ci][iy + ky][ix + kx] * wci[ky * 3 + kx];
                }
                acc += fmaxf(s, 0.f);
            }
        }
        a2[c][y][xo] = acc * 0.25f;
    }
    __syncthreads();

    // ---- conv3 (16->32, 3x3) + relu, 2x2 positions: 32*4 = 128 threads ----
    if (tid < 128) {
        const int c = tid / 4, p = tid % 4, dy = p / 2, dx = p % 2;
        const float* wc = &s_w3[c * 144];
        float s = s_b3[c];
        for (int ci = 0; ci < 16; ++ci) {
            const float* wci = &wc[ci * 9];
            #pragma unroll
            for (int ky = 0; ky < 3; ++ky)
                #pragma unroll
                for (int kx = 0; kx < 3; ++kx)
                    s += a2[ci][dy + ky][dx + kx] * wci[ky * 3 + kx];
        }
        a3p[c][p] = fmaxf(s, 0.f);
    }
    __syncthreads();
    if (tid < 32)
        a3[tid] = 0.25f * (a3p[tid][0] + a3p[tid][1] + a3p[tid][2] + a3p[tid][3]);
    __syncthreads();

    // ---- dense (32->10) ----
    if (tid < 10) {
        float s = s_bd[tid];
        #pragma unroll
        for (int i = 0; i < 32; ++i) s += a3[i] * s_wd[tid * 32 + i];
        logits[tid] = s;
    }
    __syncthreads();

    // ---- softmax over 10, write digit + guard copies ----
    if (tid < 10) {
        float m = -1e30f;
        #pragma unroll
        for (int j = 0; j < 10; ++j) m = fmaxf(m, logits[j]);
        float sum = 0.f;
        #pragma unroll
        for (int j = 0; j < 10; ++j) sum += __expf(logits[j] - m);
        const float p = __expf(logits[tid] - m) / sum;
        out[(size_t)img * 10 + tid] = p;
        out[(size_t)guard_off + (size_t)img * 10 + tid] = p;
    }
}

// ---------------------------------------------------------------------------
// Kernel 2: ordered chunk products of eff[t] = sum_g guard[t,g]*complete[g].
// One block per chunk of 64 steps; partial 10x10 product -> d_ws.
// complete[g] rebuilt per block (cheap): softmax(trans/0.1) rows + acc row.
// ---------------------------------------------------------------------------
#define CHAIN_L 64

__global__ __launch_bounds__(128) void chain_kernel(
    const float* __restrict__ guards,   // [T,10] (digit region of d_out)
    const float* __restrict__ trans,    // [10,9,10]
    float* __restrict__ partials,       // [nchunks,10,10]
    int T)
{
    __shared__ float comp[1000];              // complete[10][10][10]
    __shared__ float g_s[CHAIN_L * 10];
    __shared__ float P[100], E[100], Pn[100];

    const int tid  = threadIdx.x;
    const int base = blockIdx.x * CHAIN_L;
    const int nst  = min(CHAIN_L, T - base);

    // build complete matrices
    if (tid < 90) {
        const int g = tid / 9, i = tid % 9;
        const float* row = trans + (g * 9 + i) * 10;
        float v[10], m = -1e30f;
        #pragma unroll
        for (int j = 0; j < 10; ++j) { v[j] = row[j]; m = fmaxf(m, v[j]); }
        float e[10], sum = 0.f;
        #pragma unroll
        for (int j = 0; j < 10; ++j) { e[j] = __expf((v[j] - m) * 10.f); sum += e[j]; }
        const float inv = 1.f / sum;
        #pragma unroll
        for (int j = 0; j < 10; ++j) comp[g * 100 + i * 10 + j] = e[j] * inv;
    } else if (tid < 100) {
        const int g = tid - 90;
        #pragma unroll
        for (int j = 0; j < 10; ++j) comp[g * 100 + 90 + j] = (j == 9) ? 1.f : 0.f;
    }
    // stage guard chunk
    for (int i = tid; i < nst * 10; i += 128) g_s[i] = guards[(size_t)base * 10 + i];
    // P = I
    if (tid < 100) P[tid] = (tid / 10 == tid % 10) ? 1.f : 0.f;
    __syncthreads();

    for (int t = 0; t < nst; ++t) {
        if (tid < 100) {                       // E = sum_g guard[g]*complete[g]
            float e = 0.f;
            #pragma unroll
            for (int g = 0; g < 10; ++g) e += g_s[t * 10 + g] * comp[g * 100 + tid];
            E[tid] = e;
        }
        __syncthreads();
        if (tid < 100) {                       // Pn = P @ E
            const int i = tid / 10, j = tid % 10;
            float s = 0.f;
            #pragma unroll
            for (int k = 0; k < 10; ++k) s += P[i * 10 + k] * E[k * 10 + j];
            Pn[tid] = s;
        }
        __syncthreads();
        if (tid < 100) P[tid] = Pn[tid];
        __syncthreads();
    }
    if (tid < 100) partials[(size_t)blockIdx.x * 100 + tid] = P[tid];
}

// ---------------------------------------------------------------------------
// Kernel 3: fold chunk partials in order: s = e0 @ P_0 @ P_1 @ ...
// ---------------------------------------------------------------------------
__global__ __launch_bounds__(64) void finalize_kernel(
    const float* __restrict__ partials, float* __restrict__ out_final, int nchunks)
{
    __shared__ float s[10], sn[10];
    const int tid = threadIdx.x;
    if (tid < 10) s[tid] = (tid == 0) ? 1.f : 0.f;
    __syncthreads();
    for (int b = 0; b < nchunks; ++b) {
        if (tid < 10) {
            float acc = 0.f;
            #pragma unroll
            for (int k = 0; k < 10; ++k)
                acc += s[k] * partials[(size_t)b * 100 + k * 10 + tid];
            sn[tid] = acc;
        }
        __syncthreads();
        if (tid < 10) s[tid] = sn[tid];
        __syncthreads();
    }
    if (tid < 10) out_final[tid] = s[tid];
}

extern "C" void kernel_launch(void* const* d_in, const int* in_sizes, int n_in,
                              void* d_out, int out_size, void* d_ws, size_t ws_size,
                              hipStream_t stream)
{
    const float* seq = (const float*)d_in[0];
    const float* w1  = (const float*)d_in[1];
    const float* b1  = (const float*)d_in[2];
    const float* w2  = (const float*)d_in[3];
    const float* b2  = (const float*)d_in[4];
    const float* w3  = (const float*)d_in[5];
    const float* b3  = (const float*)d_in[6];
    const float* wd  = (const float*)d_in[7];
    const float* bd  = (const float*)d_in[8];
    const float* tm  = (const float*)d_in[9];
    float* out = (float*)d_out;

    const int T = in_sizes[0] / 784;           // 8192
    const int guard_off = T * 10;              // guard_probs region
    const int final_off = 2 * T * 10;          // final_state region
    const int nchunks = (T + CHAIN_L - 1) / CHAIN_L;

    float* partials = (float*)d_ws;            // nchunks*100 floats

    cnn_kernel<<<T, 256, 0, stream>>>(seq, w1, b1, w2, b2, w3, b3, wd, bd,
                                      out, guard_off);
    chain_kernel<<<nchunks, 128, 0, stream>>>(out, tm, partials, T);
    finalize_kernel<<<1, 64, 0, stream>>>(partials, out + final_off, nchunks);
}

// Round 2
// 122.538 us; speedup vs baseline: 1.6614x; 1.6614x over previous
//
#include <hip/hip_runtime.h>
#include <hip/hip_bf16.h>

// ---------------------------------------------------------------------------
// CNN: 2 images per 256-thread block. Register-blocked convs:
//  - activations: 4x4 windows loaded LDS->regs as float2 pairs (8B aligned)
//  - weights: global->regs (L1-resident, ~24KB total), never via LDS
//  - conv1: thread=(img2, cquad2, slot64); conv2: (img2, ocquad4, pos32)
//  - conv3: (oc32, cigrp8) K-split + LDS reduce (pitch 9, conflict-free)
// ---------------------------------------------------------------------------
__global__ __launch_bounds__(256, 4) void cnn_kernel(
    const float* __restrict__ seq,
    const float* __restrict__ w1g, const float* __restrict__ b1g,
    const float* __restrict__ w2g, const float* __restrict__ b2g,
    const float* __restrict__ w3g, const float* __restrict__ b3g,
    const float* __restrict__ wdg, const float* __restrict__ bdg,
    float* __restrict__ out, int guard_off)
{
    const int tid = threadIdx.x;

    __shared__ __align__(16) float s_img[2 * 784];          // 6.3 KB
    __shared__ __align__(16) float s_a1[2 * 8 * 13 * 14];   // pitch 14, 11.6 KB
    __shared__ __align__(16) float s_a2[2 * 16 * 5 * 6];    // pitch 6,  3.8 KB
    __shared__ __align__(16) float s_part[2303];            // conv3 partials, pitch 9
    __shared__ __align__(16) float s_p2[256];               // [im][oc][sub]
    __shared__ __align__(16) float s_a3[64];                // [im][oc32]
    __shared__ float s_logits[20];

    // ---- stage 2 images (coalesced float4) ----
    {
        const float4* src = reinterpret_cast<const float4*>(seq + (size_t)blockIdx.x * 1568);
        float4* dst = reinterpret_cast<float4*>(s_img);
        for (int i = tid; i < 392; i += 256) dst[i] = src[i];
    }
    __syncthreads();

    // ================= conv1 (1->8) + relu + pool -> a1[im][8][13][13] ======
    {
        const int im = tid >> 7, cq = (tid >> 6) & 1, slot = tid & 63;
        float w[4][9], bia[4];
        #pragma unroll
        for (int cc = 0; cc < 4; ++cc) {
            bia[cc] = b1g[cq * 4 + cc];
            #pragma unroll
            for (int k = 0; k < 9; ++k) w[cc][k] = w1g[(cq * 4 + cc) * 9 + k];
        }
        for (int p = slot; p < 169; p += 64) {
            const int y = p / 13, x = p % 13;
            float win[4][4];
            #pragma unroll
            for (int r = 0; r < 4; ++r) {
                const float* rowp = &s_img[im * 784 + (2 * y + r) * 28 + 2 * x];
                const float2 lo = *reinterpret_cast<const float2*>(rowp);
                const float2 hi = *reinterpret_cast<const float2*>(rowp + 2);
                win[r][0] = lo.x; win[r][1] = lo.y; win[r][2] = hi.x; win[r][3] = hi.y;
            }
            #pragma unroll
            for (int cc = 0; cc < 4; ++cc) {
                float pool = 0.f;
                #pragma unroll
                for (int dy = 0; dy < 2; ++dy)
                #pragma unroll
                for (int dx = 0; dx < 2; ++dx) {
                    float s = bia[cc];
                    #pragma unroll
                    for (int ky = 0; ky < 3; ++ky)
                    #pragma unroll
                    for (int kx = 0; kx < 3; ++kx)
                        s = fmaf(win[dy + ky][dx + kx], w[cc][ky * 3 + kx], s);
                    pool += fmaxf(s, 0.f);
                }
                s_a1[(im * 8 + cq * 4 + cc) * 182 + y * 14 + x] = pool * 0.25f;
            }
        }
    }
    __syncthreads();

    // ================= conv2 (8->16) + relu + pool -> a2[im][16][5][5] ======
    {
        const int im = tid >> 7, q = (tid >> 5) & 3, slot = tid & 31;
        if (slot < 25) {
            const int y = slot / 5, x = slot % 5;
            float acc2[4][4];
            #pragma unroll
            for (int o = 0; o < 4; ++o)
                #pragma unroll
                for (int s = 0; s < 4; ++s) acc2[o][s] = 0.f;

            for (int ci = 0; ci < 8; ++ci) {
                float win[4][4];
                #pragma unroll
                for (int r = 0; r < 4; ++r) {
                    const float* rowp = &s_a1[(im * 8 + ci) * 182 + (2 * y + r) * 14 + 2 * x];
                    const float2 lo = *reinterpret_cast<const float2*>(rowp);
                    const float2 hi = *reinterpret_cast<const float2*>(rowp + 2);
                    win[r][0] = lo.x; win[r][1] = lo.y; win[r][2] = hi.x; win[r][3] = hi.y;
                }
                float w[4][9];
                #pragma unroll
                for (int o = 0; o < 4; ++o)
                    #pragma unroll
                    for (int k = 0; k < 9; ++k)
                        w[o][k] = w2g[((q * 4 + o) * 8 + ci) * 9 + k];
                #pragma unroll
                for (int o = 0; o < 4; ++o)
                    #pragma unroll
                    for (int dy = 0; dy < 2; ++dy)
                    #pragma unroll
                    for (int dx = 0; dx < 2; ++dx)
                        #pragma unroll
                        for (int ky = 0; ky < 3; ++ky)
                        #pragma unroll
                        for (int kx = 0; kx < 3; ++kx)
                            acc2[o][dy * 2 + dx] =
                                fmaf(win[dy + ky][dx + kx], w[o][ky * 3 + kx], acc2[o][dy * 2 + dx]);
            }
            #pragma unroll
            for (int o = 0; o < 4; ++o) {
                const float b = b2g[q * 4 + o];
                float pool = 0.f;
                #pragma unroll
                for (int s = 0; s < 4; ++s) pool += fmaxf(acc2[o][s] + b, 0.f);
                s_a2[(im * 16 + q * 4 + o) * 30 + y * 6 + x] = pool * 0.25f;
            }
        }
    }
    __syncthreads();

    // ================= conv3 (16->32) partials, K split over 8 groups ======
    {
        const int oc = tid >> 3, cg = tid & 7;
        float w[2][9];
        #pragma unroll
        for (int cc = 0; cc < 2; ++cc)
            #pragma unroll
            for (int k = 0; k < 9; ++k)
                w[cc][k] = w3g[(oc * 16 + 2 * cg + cc) * 9 + k];
        float pacc[2][4];
        #pragma unroll
        for (int i = 0; i < 2; ++i)
            #pragma unroll
            for (int s = 0; s < 4; ++s) pacc[i][s] = 0.f;

        #pragma unroll
        for (int cc = 0; cc < 2; ++cc) {
            const int ci = 2 * cg + cc;
            #pragma unroll
            for (int im = 0; im < 2; ++im) {
                float win[4][4];
                #pragma unroll
                for (int r = 0; r < 4; ++r) {
                    const float* rowp = &s_a2[(im * 16 + ci) * 30 + r * 6];
                    const float2 lo = *reinterpret_cast<const float2*>(rowp);
                    const float2 hi = *reinterpret_cast<const float2*>(rowp + 2);
                    win[r][0] = lo.x; win[r][1] = lo.y; win[r][2] = hi.x; win[r][3] = hi.y;
                }
                #pragma unroll
                for (int dy = 0; dy < 2; ++dy)
                #pragma unroll
                for (int dx = 0; dx < 2; ++dx)
                    #pragma unroll
                    for (int ky = 0; ky < 3; ++ky)
                    #pragma unroll
                    for (int kx = 0; kx < 3; ++kx)
                        pacc[im][dy * 2 + dx] =
                            fmaf(win[dy + ky][dx + kx], w[cc][ky * 3 + kx], pacc[im][dy * 2 + dx]);
            }
        }
        #pragma unroll
        for (int im = 0; im < 2; ++im)
            #pragma unroll
            for (int s = 0; s < 4; ++s)
                s_part[((oc * 4 + s) * 2 + im) * 9 + cg] = pacc[im][s];
    }
    __syncthreads();

    // reduce 8 partials per (oc,sub,im), relu -> p2[im][oc][sub]
    {
        const int oc = tid >> 3, sub = (tid >> 1) & 3, im = tid & 1;
        const float* pp = &s_part[tid * 9];
        float sum = b3g[oc];
        #pragma unroll
        for (int k = 0; k < 8; ++k) sum += pp[k];
        s_p2[im * 128 + oc * 4 + sub] = fmaxf(sum, 0.f);
    }
    __syncthreads();

    if (tid < 64) {   // avgpool 2x2 -> a3[im][oc]
        const int im = tid >> 5, oc = tid & 31;
        const float4 t = *reinterpret_cast<const float4*>(&s_p2[im * 128 + oc * 4]);
        s_a3[im * 32 + oc] = 0.25f * (t.x + t.y + t.z + t.w);
    }
    __syncthreads();

    if (tid < 20) {   // dense 32->10
        const int im = (tid >= 10), j = tid - im * 10;
        float s = bdg[j];
        #pragma unroll
        for (int i = 0; i < 32; ++i) s = fmaf(s_a3[im * 32 + i], wdg[j * 32 + i], s);
        s_logits[im * 10 + j] = s;
    }
    __syncthreads();

    if (tid < 20) {   // softmax + write digit & guard copies
        const int im = (tid >= 10), j = tid - im * 10;
        const float* lg = &s_logits[im * 10];
        float m = -1e30f;
        #pragma unroll
        for (int k = 0; k < 10; ++k) m = fmaxf(m, lg[k]);
        float sum = 0.f;
        #pragma unroll
        for (int k = 0; k < 10; ++k) sum += __expf(lg[k] - m);
        const float p = __expf(lg[j] - m) / sum;
        const size_t gi = (size_t)(blockIdx.x * 2 + im) * 10 + j;
        out[gi] = p;
        out[(size_t)guard_off + gi] = p;
    }
}

// ---------------------------------------------------------------------------
// Kernel 2: ordered chunk products of eff[t] = sum_g guard[t,g]*complete[g].
// ---------------------------------------------------------------------------
#define CHAIN_L 64

__global__ __launch_bounds__(128) void chain_kernel(
    const float* __restrict__ guards,   // [T,10]
    const float* __restrict__ trans,    // [10,9,10]
    float* __restrict__ partials,       // [nchunks,10,10]
    int T)
{
    __shared__ float comp[1000];
    __shared__ float g_s[CHAIN_L * 10];
    __shared__ float P[100], E[100], Pn[100];

    const int tid  = threadIdx.x;
    const int base = blockIdx.x * CHAIN_L;
    const int nst  = min(CHAIN_L, T - base);

    if (tid < 90) {
        const int g = tid / 9, i = tid % 9;
        const float* row = trans + (g * 9 + i) * 10;
        float v[10], m = -1e30f;
        #pragma unroll
        for (int j = 0; j < 10; ++j) { v[j] = row[j]; m = fmaxf(m, v[j]); }
        float e[10], sum = 0.f;
        #pragma unroll
        for (int j = 0; j < 10; ++j) { e[j] = __expf((v[j] - m) * 10.f); sum += e[j]; }
        const float inv = 1.f / sum;
        #pragma unroll
        for (int j = 0; j < 10; ++j) comp[g * 100 + i * 10 + j] = e[j] * inv;
    } else if (tid < 100) {
        const int g = tid - 90;
        #pragma unroll
        for (int j = 0; j < 10; ++j) comp[g * 100 + 90 + j] = (j == 9) ? 1.f : 0.f;
    }
    for (int i = tid; i < nst * 10; i += 128) g_s[i] = guards[(size_t)base * 10 + i];
    if (tid < 100) P[tid] = (tid / 10 == tid % 10) ? 1.f : 0.f;
    __syncthreads();

    for (int t = 0; t < nst; ++t) {
        if (tid < 100) {
            float e = 0.f;
            #pragma unroll
            for (int g = 0; g < 10; ++g) e += g_s[t * 10 + g] * comp[g * 100 + tid];
            E[tid] = e;
        }
        __syncthreads();
        if (tid < 100) {
            const int i = tid / 10, j = tid % 10;
            float s = 0.f;
            #pragma unroll
            for (int k = 0; k < 10; ++k) s += P[i * 10 + k] * E[k * 10 + j];
            Pn[tid] = s;
        }
        __syncthreads();
        if (tid < 100) P[tid] = Pn[tid];
        __syncthreads();
    }
    if (tid < 100) partials[(size_t)blockIdx.x * 100 + tid] = P[tid];
}

// ---------------------------------------------------------------------------
// Kernel 3: fold partials in order. LDS-staged to kill serial global latency.
// ---------------------------------------------------------------------------
__global__ __launch_bounds__(64) void finalize_kernel(
    const float* __restrict__ partials, float* __restrict__ out_final, int nchunks)
{
    __shared__ __align__(16) float sp[12800];   // up to 128 chunk matrices
    __shared__ float s[10], sn[10];
    const int tid = threadIdx.x;
    const int total = nchunks * 100;
    for (int i = tid * 4; i < total; i += 256)
        *reinterpret_cast<float4*>(&sp[i]) = *reinterpret_cast<const float4*>(&partials[i]);
    if (tid < 10) s[tid] = (tid == 0) ? 1.f : 0.f;
    __syncthreads();
    for (int b = 0; b < nchunks; ++b) {
        if (tid < 10) {
            float a = 0.f;
            #pragma unroll
            for (int k = 0; k < 10; ++k) a += s[k] * sp[b * 100 + k * 10 + tid];
            sn[tid] = a;
        }
        __syncthreads();
        if (tid < 10) s[tid] = sn[tid];
        __syncthreads();
    }
    if (tid < 10) out_final[tid] = s[tid];
}

extern "C" void kernel_launch(void* const* d_in, const int* in_sizes, int n_in,
                              void* d_out, int out_size, void* d_ws, size_t ws_size,
                              hipStream_t stream)
{
    const float* seq = (const float*)d_in[0];
    const float* w1  = (const float*)d_in[1];
    const float* b1  = (const float*)d_in[2];
    const float* w2  = (const float*)d_in[3];
    const float* b2  = (const float*)d_in[4];
    const float* w3  = (const float*)d_in[5];
    const float* b3  = (const float*)d_in[6];
    const float* wd  = (const float*)d_in[7];
    const float* bd  = (const float*)d_in[8];
    const float* tm  = (const float*)d_in[9];
    float* out = (float*)d_out;

    const int T = in_sizes[0] / 784;           // 8192
    const int guard_off = T * 10;
    const int final_off = 2 * T * 10;
    const int nchunks = (T + CHAIN_L - 1) / CHAIN_L;   // 128

    float* partials = (float*)d_ws;

    cnn_kernel<<<T / 2, 256, 0, stream>>>(seq, w1, b1, w2, b2, w3, b3, wd, bd,
                                          out, guard_off);
    chain_kernel<<<nchunks, 128, 0, stream>>>(out, tm, partials, T);
    finalize_kernel<<<1, 64, 0, stream>>>(partials, out + final_off, nchunks);
}